// Round 1
// 2072.502 us; speedup vs baseline: 1.1805x; 1.1805x over previous
//
#include <hip/hip_runtime.h>
#include <hip/hip_bf16.h>

#define H 4096
#define MOE_I 1024
#define SH_I 4096
#define NE 16
#define T_TOK 4096
#define NPAIR 8192

using bf16x8 = __attribute__((ext_vector_type(8))) short;
using f32x4  = __attribute__((ext_vector_type(4))) float;

__device__ __forceinline__ unsigned short f2bf(float f) {
    unsigned int x = __float_as_uint(f);
    x += 0x7fffu + ((x >> 16) & 1u);   // round-to-nearest-even
    return (unsigned short)(x >> 16);
}
__device__ __forceinline__ float bf2f(unsigned short u) {
    return __uint_as_float(((unsigned int)u) << 16);
}

__device__ __forceinline__ void gld_lds16(const void* g, void* l) {
    __builtin_amdgcn_global_load_lds(
        (const __attribute__((address_space(1))) void*)g,
        (__attribute__((address_space(3))) void*)l, 16, 0, 0);
}

// ---------------- cast fp32 -> bf16 (vectorized) ----------------
__global__ __launch_bounds__(256)
void cast_kernel(const float4* __restrict__ src, ushort4* __restrict__ dst, int n4) {
    int i = blockIdx.x * 256 + threadIdx.x;
    if (i < n4) {
        float4 f = src[i];
        ushort4 o;
        o.x = f2bf(f.x); o.y = f2bf(f.y); o.z = f2bf(f.z); o.w = f2bf(f.w);
        dst[i] = o;
    }
}

// ---------------- router: logits -> top2 -> weights + histogram ----------------
__global__ __launch_bounds__(256)
void router_kernel(const float* __restrict__ x, const float* __restrict__ gw,
                   int* __restrict__ topk_id, float* __restrict__ topk_w,
                   int* __restrict__ counts) {
    int t = blockIdx.x;
    const float* xr = x + (size_t)t * H;
    __shared__ float lg[NE];
    int tid = threadIdx.x, w = tid >> 6, lane = tid & 63;
#pragma unroll
    for (int i = 0; i < 4; i++) {
        int e = w * 4 + i;
        const float* g = gw + (size_t)e * H;
        float s = 0.f;
        for (int k = lane; k < H; k += 64) s += xr[k] * g[k];
#pragma unroll
        for (int m = 32; m > 0; m >>= 1) s += __shfl_xor(s, m, 64);
        if (lane == 0) lg[e] = s;
    }
    __syncthreads();
    if (tid == 0) {
        int e0 = 0; float l0 = lg[0];
        for (int e = 1; e < NE; e++) if (lg[e] > l0) { l0 = lg[e]; e0 = e; }
        int e1 = -1; float l1 = -1e30f;
        for (int e = 0; e < NE; e++) if (e != e0 && lg[e] > l1) { l1 = lg[e]; e1 = e; }
        float w1 = 1.f / (1.f + __expf(l0 - l1));
        topk_id[2*t] = e0; topk_id[2*t+1] = e1;
        topk_w[2*t] = 1.f - w1; topk_w[2*t+1] = w1;
        atomicAdd(&counts[e0], 1); atomicAdd(&counts[e1], 1);
    }
}

__global__ void scan16(const int* __restrict__ counts, int* __restrict__ offsets,
                       int* __restrict__ cursor) {
    if (threadIdx.x == 0 && blockIdx.x == 0) {
        int s = 0;
        for (int e = 0; e < NE; e++) { offsets[e] = s; cursor[e] = s; s += counts[e]; }
        offsets[NE] = s;
    }
}

__global__ __launch_bounds__(256)
void assign_kernel(const int* __restrict__ topk_id, const float* __restrict__ topk_w,
                   int* __restrict__ cursor, int* __restrict__ perm_tok,
                   float* __restrict__ perm_w) {
    int t = blockIdx.x * blockDim.x + threadIdx.x;
    if (t >= T_TOK) return;
    for (int k = 0; k < 2; k++) {
        int e = topk_id[2*t+k];
        int pos = atomicAdd(&cursor[e], 1);
        perm_tok[pos] = t;
        perm_w[pos] = topk_w[2*t+k];
    }
}

// ---------------- 256x256 bf16 MFMA GEMM, 8-phase pipelined, C = A @ B^T ----------------
// 512 threads = 8 waves (2 M x 4 N), BK=64 (2 k-slices of 32), 128 KiB LDS (2 bufs).
// LDS layout per buf (65536 B): A at +0, B at +32768; each as [khalf][256 rows][32 cols] bf16,
// with XOR swizzle: 16B slot index ^= (row>>1)&3 (pre-swizzled global source, swizzled ds_read).
// MODE 0: plain, bf16 store    MODE 1: plain, fp32 store
// MODE 2: A rows gathered via perm_tok, bf16 store at off+row
// MODE 3: A rows = off+row, epilogue atomicAdd(Cf[perm_tok], perm_w * v)
template<int MODE>
__global__ __launch_bounds__(512, 2)
void gemm8(const unsigned short* __restrict__ A0,
           const unsigned short* __restrict__ B0,
           unsigned short* __restrict__ Cb, float* __restrict__ Cf,
           const int* __restrict__ offsets, const int* __restrict__ perm_tok,
           const float* __restrict__ perm_w,
           int K, int N, int M, int ldc) {
    extern __shared__ char smem[];
    int e = 0, off = 0, cnt = M;
    if constexpr (MODE >= 2) { e = blockIdx.z; off = offsets[e]; cnt = offsets[e + 1] - off; }
    const int m0 = blockIdx.y * 256, n0 = blockIdx.x * 256;
    if (m0 >= cnt) return;
    const unsigned short* Bp = B0 + (size_t)e * N * K;

    const int tid = threadIdx.x, w = tid >> 6, lane = tid & 63;
    const int wr = w >> 2, wc = w & 3;          // wave tile: 128 rows x 64 cols
    const int quad = lane >> 4, r16 = lane & 15;

    // ---- staging setup: per (khalf, issue) source ptrs (pre-swizzled) + wave-uniform LDS dests
    const unsigned short* srcA[2][2];
    const unsigned short* srcB[2][2];
    int dstA[2][2], dstB[2][2];
#pragma unroll
    for (int kh = 0; kh < 2; kh++)
#pragma unroll
        for (int j = 0; j < 2; j++) {
            int D  = (j * 8 + w) * 1024 + lane * 16;   // linear byte dest within 16KB chunk
            int r  = D >> 6;                           // tile row 0..255
            int sl = (D >> 4) & 3;
            int sg = sl ^ ((r >> 1) & 3);              // swizzled source slot
            int ra = m0 + r; if (ra > cnt - 1) ra = cnt - 1;
            int rs;
            if constexpr (MODE == 2)      rs = perm_tok[off + ra];
            else if constexpr (MODE == 3) rs = off + ra;
            else                          rs = ra;
            srcA[kh][j] = A0 + (size_t)rs * K + kh * 32 + sg * 8;
            srcB[kh][j] = Bp + (size_t)(n0 + r) * K + kh * 32 + sg * 8;
            dstA[kh][j] = kh * 16384 + (j * 8 + w) * 1024;
            dstB[kh][j] = 32768 + dstA[kh][j];
        }

    // ---- ds_read addressing (swizzled): byte = [A:0|B:32768] + ks*16384 + row*64 + slot*16
    const int swz  = (quad ^ ((r16 >> 1) & 3)) * 16;
    const int aoff = (wr * 128 + r16) * 64 + swz;
    const int boff = 32768 + (wc * 64 + r16) * 64 + swz;

    f32x4 acc[8][4];
#pragma unroll
    for (int i = 0; i < 8; i++)
#pragma unroll
        for (int j = 0; j < 4; j++) acc[i][j] = (f32x4){0.f, 0.f, 0.f, 0.f};

    const int nt = K >> 6;

    // ---- prologue: stage tile 0 -> buf0; issue order per tile: A-K0(2), B-K0(2), A-K1(2), B-K1(2)
#pragma unroll
    for (int kh = 0; kh < 2; kh++) {
        gld_lds16(srcA[kh][0], smem + dstA[kh][0]);
        gld_lds16(srcA[kh][1], smem + dstA[kh][1]);
        gld_lds16(srcB[kh][0], smem + dstB[kh][0]);
        gld_lds16(srcB[kh][1], smem + dstB[kh][1]);
    }
    {
        int adv0 = (nt > 1) ? 64 : 0;
#pragma unroll
        for (int kh = 0; kh < 2; kh++)
#pragma unroll
            for (int j = 0; j < 2; j++) { srcA[kh][j] += adv0; srcB[kh][j] += adv0; }
    }

    for (int t = 0; t < nt; t++) {
        char* sb = smem + (t & 1) * 65536;          // compute buffer
        char* so = smem + ((t + 1) & 1) * 65536;    // stage target (tile t+1)
        const int adv = (t + 2 < nt) ? 64 : 0;
        bf16x8 av[4], bv[4];

        // ===== boundary: own A-K0,B-K0 of tile t landed (oldest 4 of 8 outstanding) =====
        asm volatile("s_waitcnt vmcnt(4)" ::: "memory");
        __builtin_amdgcn_s_barrier();
        asm volatile("" ::: "memory");
        // ----- P1: stage A-K0(t+1); compute ks=0, rows m0-3, all n -----
        gld_lds16(srcA[0][0], so + dstA[0][0]);
        gld_lds16(srcA[0][1], so + dstA[0][1]);
        srcA[0][0] += adv; srcA[0][1] += adv;
#pragma unroll
        for (int mi = 0; mi < 4; mi++) av[mi] = *(const bf16x8*)(sb + mi * 1024 + aoff);
#pragma unroll
        for (int ni = 0; ni < 4; ni++) bv[ni] = *(const bf16x8*)(sb + ni * 1024 + boff);
        __builtin_amdgcn_s_setprio(1);
#pragma unroll
        for (int mi = 0; mi < 4; mi++)
#pragma unroll
            for (int ni = 0; ni < 4; ni++)
                acc[mi][ni] = __builtin_amdgcn_mfma_f32_16x16x32_bf16(
                    av[mi], bv[ni], acc[mi][ni], 0, 0, 0);
        __builtin_amdgcn_s_setprio(0);
        // ----- P2: stage B-K0(t+1); compute ks=0, rows m4-7 (reuse bv) -----
        gld_lds16(srcB[0][0], so + dstB[0][0]);
        gld_lds16(srcB[0][1], so + dstB[0][1]);
        srcB[0][0] += adv; srcB[0][1] += adv;
#pragma unroll
        for (int mi = 0; mi < 4; mi++) av[mi] = *(const bf16x8*)(sb + (mi + 4) * 1024 + aoff);
        __builtin_amdgcn_s_setprio(1);
#pragma unroll
        for (int mi = 0; mi < 4; mi++)
#pragma unroll
            for (int ni = 0; ni < 4; ni++)
                acc[mi + 4][ni] = __builtin_amdgcn_mfma_f32_16x16x32_bf16(
                    av[mi], bv[ni], acc[mi + 4][ni], 0, 0, 0);
        __builtin_amdgcn_s_setprio(0);

        // ===== mid: own A-K1,B-K1 of tile t landed (oldest 4 of 8 outstanding) =====
        asm volatile("s_waitcnt vmcnt(4)" ::: "memory");
        __builtin_amdgcn_s_barrier();
        asm volatile("" ::: "memory");
        // ----- P3: stage A-K1(t+1); compute ks=1, rows m0-3 -----
        gld_lds16(srcA[1][0], so + dstA[1][0]);
        gld_lds16(srcA[1][1], so + dstA[1][1]);
        srcA[1][0] += adv; srcA[1][1] += adv;
#pragma unroll
        for (int mi = 0; mi < 4; mi++) av[mi] = *(const bf16x8*)(sb + 16384 + mi * 1024 + aoff);
#pragma unroll
        for (int ni = 0; ni < 4; ni++) bv[ni] = *(const bf16x8*)(sb + 16384 + ni * 1024 + boff);
        __builtin_amdgcn_s_setprio(1);
#pragma unroll
        for (int mi = 0; mi < 4; mi++)
#pragma unroll
            for (int ni = 0; ni < 4; ni++)
                acc[mi][ni] = __builtin_amdgcn_mfma_f32_16x16x32_bf16(
                    av[mi], bv[ni], acc[mi][ni], 0, 0, 0);
        __builtin_amdgcn_s_setprio(0);
        // ----- P4: stage B-K1(t+1); compute ks=1, rows m4-7 -----
        gld_lds16(srcB[1][0], so + dstB[1][0]);
        gld_lds16(srcB[1][1], so + dstB[1][1]);
        srcB[1][0] += adv; srcB[1][1] += adv;
#pragma unroll
        for (int mi = 0; mi < 4; mi++) av[mi] = *(const bf16x8*)(sb + 16384 + (mi + 4) * 1024 + aoff);
        __builtin_amdgcn_s_setprio(1);
#pragma unroll
        for (int mi = 0; mi < 4; mi++)
#pragma unroll
            for (int ni = 0; ni < 4; ni++)
                acc[mi + 4][ni] = __builtin_amdgcn_mfma_f32_16x16x32_bf16(
                    av[mi], bv[ni], acc[mi + 4][ni], 0, 0, 0);
        __builtin_amdgcn_s_setprio(0);
    }

    // drain all LDS-DMA before workgroup can exit / epilogue
    asm volatile("s_waitcnt vmcnt(0)" ::: "memory");

    // ---- epilogue: C/D layout col = lane&15, row = quad*4 + reg ----
    const int rowlim = cnt - m0;
#pragma unroll
    for (int mi = 0; mi < 8; mi++) {
#pragma unroll
        for (int rr = 0; rr < 4; rr++) {
            int r = wr * 128 + mi * 16 + quad * 4 + rr;
            if (r < rowlim) {
                int tok = 0; float wt = 0.f;
                if constexpr (MODE == 3) {
                    tok = perm_tok[off + m0 + r];
                    wt  = perm_w[off + m0 + r];
                }
#pragma unroll
                for (int ni = 0; ni < 4; ni++) {
                    int col = n0 + wc * 64 + ni * 16 + r16;
                    float v = acc[mi][ni][rr];
                    if constexpr (MODE == 0)
                        Cb[(size_t)(m0 + r) * ldc + col] = f2bf(v);
                    else if constexpr (MODE == 1)
                        Cf[(size_t)(m0 + r) * ldc + col] = v;
                    else if constexpr (MODE == 2)
                        Cb[(size_t)(off + m0 + r) * ldc + col] = f2bf(v);
                    else
                        atomicAdd(&Cf[(size_t)tok * ldc + col], wt * v);
                }
            }
        }
    }
}

// ---------------- SwiGLU: act = silu(g) * u, bf16x8 vectorized ----------------
template<int SHIFT>  // half = 1<<SHIFT
__global__ __launch_bounds__(256)
void swiglu_kernel(const unsigned short* __restrict__ gu, unsigned short* __restrict__ act,
                   long long total) {
    long long idx = ((long long)blockIdx.x * 256 + threadIdx.x) * 8;
    if (idx >= total) return;
    const int half = 1 << SHIFT;
    long long row = idx >> SHIFT;
    int cb = (int)(idx & (half - 1));
    const unsigned short* gp = gu + (row << (SHIFT + 1)) + cb;
    bf16x8 g8 = *(const bf16x8*)gp;
    bf16x8 u8 = *(const bf16x8*)(gp + half);
    bf16x8 res;
#pragma unroll
    for (int i = 0; i < 8; i++) {
        float g = bf2f((unsigned short)g8[i]);
        float u = bf2f((unsigned short)u8[i]);
        float a = g / (1.f + __expf(-g));
        res[i] = (short)f2bf(a * u);
    }
    *(bf16x8*)(act + idx) = res;
}

extern "C" void kernel_launch(void* const* d_in, const int* in_sizes, int n_in,
                              void* d_out, int out_size, void* d_ws, size_t ws_size,
                              hipStream_t stream) {
    const float* x         = (const float*)d_in[0];
    const float* gate_w    = (const float*)d_in[1];
    const float* w_gate_up = (const float*)d_in[2];
    const float* w_down    = (const float*)d_in[3];
    const float* s_wgu     = (const float*)d_in[4];
    const float* s_wd      = (const float*)d_in[5];
    float* out = (float*)d_out;

    char* p = (char*)d_ws;
    auto alloc = [&](size_t bytes) {
        char* q = p;
        p += (bytes + 255) & ~(size_t)255;
        return q;
    };
    unsigned short* x_bf    = (unsigned short*)alloc((size_t)T_TOK * H * 2);
    unsigned short* wgu_bf  = (unsigned short*)alloc((size_t)NE * 2 * MOE_I * H * 2);
    unsigned short* wd_bf   = (unsigned short*)alloc((size_t)NE * H * MOE_I * 2);
    unsigned short* swgu_bf = (unsigned short*)alloc((size_t)2 * SH_I * H * 2);
    unsigned short* swd_bf  = (unsigned short*)alloc((size_t)H * SH_I * 2);
    unsigned short* gu_s    = (unsigned short*)alloc((size_t)T_TOK * 2 * SH_I * 2);
    unsigned short* act_s   = (unsigned short*)alloc((size_t)T_TOK * SH_I * 2);
    unsigned short* gu_e    = (unsigned short*)alloc((size_t)NPAIR * 2 * MOE_I * 2);
    unsigned short* act_e   = (unsigned short*)alloc((size_t)NPAIR * MOE_I * 2);
    int*   topk_id  = (int*)alloc(T_TOK * 2 * 4);
    float* topk_w   = (float*)alloc(T_TOK * 2 * 4);
    int*   counts   = (int*)alloc(NE * 4);
    int*   offsets  = (int*)alloc((NE + 1) * 4);
    int*   cursor   = (int*)alloc(NE * 4);
    int*   perm_tok = (int*)alloc(NPAIR * 4);
    float* perm_w   = (float*)alloc(NPAIR * 4);

    // counts/offsets/cursor are three consecutive 256B-aligned slots
    hipMemsetAsync(counts, 0, 768, stream);

    const int SHMEM = 131072;
    static int attr_done = 0;
    if (!attr_done) {
        hipFuncSetAttribute((const void*)gemm8<0>, hipFuncAttributeMaxDynamicSharedMemorySize, SHMEM);
        hipFuncSetAttribute((const void*)gemm8<1>, hipFuncAttributeMaxDynamicSharedMemorySize, SHMEM);
        hipFuncSetAttribute((const void*)gemm8<2>, hipFuncAttributeMaxDynamicSharedMemorySize, SHMEM);
        hipFuncSetAttribute((const void*)gemm8<3>, hipFuncAttributeMaxDynamicSharedMemorySize, SHMEM);
        attr_done = 1;
    }

    auto cast = [&](const float* s, unsigned short* d, size_t n) {
        int n4 = (int)(n / 4);
        cast_kernel<<<(n4 + 255) / 256, 256, 0, stream>>>((const float4*)s, (ushort4*)d, n4);
    };
    cast(x, x_bf, (size_t)T_TOK * H);
    cast(w_gate_up, wgu_bf, (size_t)NE * 2 * MOE_I * H);
    cast(w_down, wd_bf, (size_t)NE * H * MOE_I);
    cast(s_wgu, swgu_bf, (size_t)2 * SH_I * H);
    cast(s_wd, swd_bf, (size_t)H * SH_I);

    router_kernel<<<T_TOK, 256, 0, stream>>>(x, gate_w, topk_id, topk_w, counts);
    scan16<<<1, 64, 0, stream>>>(counts, offsets, cursor);
    assign_kernel<<<16, 256, 0, stream>>>(topk_id, topk_w, cursor, perm_tok, perm_w);

    // shared gate_up: [4096,4096] @ [8192,4096]^T -> gu_s
    gemm8<0><<<dim3(2 * SH_I / 256, T_TOK / 256, 1), 512, SHMEM, stream>>>(
        x_bf, swgu_bf, gu_s, nullptr, nullptr, nullptr, nullptr, H, 2 * SH_I, T_TOK, 2 * SH_I);
    swiglu_kernel<12><<<(int)(((long long)T_TOK * SH_I / 8 + 255) / 256), 256, 0, stream>>>(
        gu_s, act_s, (long long)T_TOK * SH_I);
    // shared down: -> d_out (plain store, covers all elements)
    gemm8<1><<<dim3(H / 256, T_TOK / 256, 1), 512, SHMEM, stream>>>(
        act_s, swd_bf, nullptr, out, nullptr, nullptr, nullptr, SH_I, H, T_TOK, H);

    // expert gate_up (gathered A)
    gemm8<2><<<dim3(2 * MOE_I / 256, T_TOK / 256, NE), 512, SHMEM, stream>>>(
        x_bf, wgu_bf, gu_e, nullptr, offsets, perm_tok, nullptr, H, 2 * MOE_I, 0, 2 * MOE_I);
    swiglu_kernel<10><<<(int)(((long long)NPAIR * MOE_I / 8 + 255) / 256), 256, 0, stream>>>(
        gu_e, act_e, (long long)NPAIR * MOE_I);
    // expert down: scatter-atomicAdd onto d_out (after shared down)
    gemm8<3><<<dim3(H / 256, T_TOK / 256, NE), 512, SHMEM, stream>>>(
        act_e, wd_bf, nullptr, out, offsets, perm_tok, perm_w, MOE_I, H, 0, H);
}